// Round 4
// baseline (3799.350 us; speedup 1.0000x reference)
//
#include <hip/hip_runtime.h>

#define Bn 2048
#define Hn 1024
#define Ln 96
#define Vn 96

typedef short bf16x8 __attribute__((ext_vector_type(8)));
typedef float f32x4 __attribute__((ext_vector_type(4)));

// counted waits (T4): immediates must be literals
#define VM_WAIT(n) asm volatile("s_waitcnt vmcnt(" #n ")" ::: "memory")
#define LGKM_WAIT0 asm volatile("s_waitcnt lgkmcnt(0)" ::: "memory")

__device__ __forceinline__ void async16(const void* g, void* l)
{
    __builtin_amdgcn_global_load_lds(
        (const __attribute__((address_space(1))) void*)g,
        (__attribute__((address_space(3))) void*)l, 16, 0, 0);
}

__device__ __forceinline__ unsigned short f2bf(float f)
{
    unsigned u = __float_as_uint(f);
    u += 0x7fff + ((u >> 16) & 1);          // round-to-nearest-even
    return (unsigned short)(u >> 16);
}

__device__ __forceinline__ float bf2f(unsigned short s)
{
    return __uint_as_float(((unsigned)s) << 16);
}

__device__ __forceinline__ float fast_tanh(float x)
{
    float e = __expf(2.0f * x);
    return 1.0f - __fdividef(2.0f, e + 1.0f);
}

// ---------------------------------------------------------------------------
// Fused step kernel, launch index s (0..97). Grid = 1056 x 128 thr.
// XCD-PINNED decode (blocks round-robin XCDs by bid%8; 1056 = 132 x 8):
//   xcd = bid&7, l = bid>>3 in [0,132):
//     l in [0,64)   : L1(t=s-1), iBase = (xcd*2 + (l&1))*64, bBase = (l>>1)*64
//     l in [64,128) : L0(t=s),   same decode on l-64
//     l in [128,132): FC(t=s-2), bBase = ((l-128)*8 + xcd)*64
// => each XCD sees only 2/16 weight-column panels of W0/W1i/W1h (768 KB,
//    L2-resident across launches); consecutive local bids (i-minor) share the
//    same A-panel so its second read is an L2 hit. Per-XCD work is identical
//    (64 L1 + 64 L0 + 4 FC) -> balanced.
// Roles: L1 dual GEMM (wave0 = h0@W1i^T, wave1 = h1@W1h^T, f32 LDS reduce);
//        L0 split-K across waves; FC split-K. All roles read only
//        prior-launch buffers -> no intra-launch ordering.
// K-loop BARRIER-FREE (per-wave private LDS), depth-2 pipeline: 3 bufs/wave,
// stage chunk kc+2 while computing kc, counted s_waitcnt vmcnt(16).
// LDS slots XOR-swizzled on BOTH global source column and ds_read address.
// LDS 48 KB -> 3 blocks/CU.
// ---------------------------------------------------------------------------
__global__ __launch_bounds__(128, 2) void fused_step(
    int s,
    const unsigned short* __restrict__ H0rd, unsigned short* __restrict__ H0wr,
    const unsigned short* __restrict__ H1rd, unsigned short* __restrict__ H1wr,
    const unsigned short* __restrict__ W0b,
    const unsigned short* __restrict__ W1ib, const unsigned short* __restrict__ W1hb,
    const unsigned short* __restrict__ fcWb,
    const float* __restrict__ w0ih,
    const float* __restrict__ b0i, const float* __restrict__ b0h,
    const float* __restrict__ b1i, const float* __restrict__ b1h,
    const float* __restrict__ fcb, const float* __restrict__ x,
    float* __restrict__ out)
{
    __shared__ __align__(16) unsigned short smem[24576];   // 48 KB
    const int tid = threadIdx.x;
    const int lane = tid & 63;
    const int wave = tid >> 6;
    const int srow = lane >> 2;                 // staging row within 16-row chunk
    // stage-side swizzle: lane stores slot (lane&3), fetches global slot
    // (lane&3) ^ g(srow), g(row) = (row>>1)&3  [bijective per row]
    const int scol = ((lane & 3) ^ ((lane >> 3) & 3)) * 8;  // bf16 elems
    const int lr = lane & 15;
    const int lq = lane >> 4;
    // read-side swizzle: global slot lq of row lr lives at stored slot lq^g(lr)
    const int roff = lr * 32 + ((lq ^ ((lr >> 1) & 3)) * 8);
    const int bid = blockIdx.x;
    const int xcd = bid & 7;
    const int l   = bid >> 3;                   // [0,132)

    if (l < 128) {
        // ========== L1 (l<64) / L0 (l>=64): 64x64 tile, XCD-pinned cols ====
        const bool isL1 = (l < 64);
        if (isL1) { if (s < 1 || s > 96) return; }
        else      { if (s > 95) return; }
        const int ll = l & 63;
        const int bBase = (ll >> 1) * 64;                 // b-major
        const int iBase = (xcd * 2 + (ll & 1)) * 64;      // i-minor, XCD-pinned
        // L1: each wave does a full-K GEMM on its own (A,B) pair.
        // L0: split-K, wave w covers K [w*512, w*512+512).
        const int NIT = isL1 ? 32 : 16;
        const int k0 = isL1 ? 0 : wave * 512;
        const unsigned short* Ag = isL1 ? (wave ? H1rd : H0rd) : H0rd;
        const unsigned short* Bg = isL1 ? (wave ? W1hb : W1ib) : W0b;

        unsigned short* const Al = smem + wave * 6144;           // 3 bufs x 2048
        unsigned short* const Bl = smem + 12288 + wave * 6144;   // 3 bufs x 2048

        f32x4 acc[4][4];
#pragma unroll
        for (int i = 0; i < 4; ++i)
#pragma unroll
            for (int j = 0; j < 4; ++j) acc[i][j] = (f32x4){0.f, 0.f, 0.f, 0.f};

        auto stage = [&](int ks, int sb) {
            const int koff = k0 + ks * 32;
#pragma unroll
            for (int c = 0; c < 4; ++c) {
                async16(Ag + (size_t)(bBase + c * 16 + srow) * Hn + koff + scol,
                        Al + sb * 2048 + c * 512);
                async16(Bg + (size_t)(iBase + c * 16 + srow) * Hn + koff + scol,
                        Bl + sb * 2048 + c * 512);
            }
        };

        stage(0, 0);
        stage(1, 1);
        int cur = 0;
        for (int it = 0; it < NIT; ++it) {
            int stb = cur + 2; if (stb >= 3) stb -= 3;
            if (it + 2 < NIT) { LGKM_WAIT0; stage(it + 2, stb); VM_WAIT(16); }
            else if (it + 1 < NIT) VM_WAIT(8);
            else                   VM_WAIT(0);
            bf16x8 a[4], b[4];
#pragma unroll
            for (int i = 0; i < 4; ++i) {
                a[i] = *(const bf16x8*)(Al + cur * 2048 + i * 512 + roff);
                b[i] = *(const bf16x8*)(Bl + cur * 2048 + i * 512 + roff);
            }
            __builtin_amdgcn_s_setprio(1);
#pragma unroll
            for (int mt = 0; mt < 4; ++mt)
#pragma unroll
                for (int nt = 0; nt < 4; ++nt)
                    acc[mt][nt] = __builtin_amdgcn_mfma_f32_16x16x32_bf16(
                        a[mt], b[nt], acc[mt][nt], 0, 0, 0);
            __builtin_amdgcn_s_setprio(0);
            cur = (cur == 2) ? 0 : cur + 1;
        }
        __syncthreads();                        // staging done; alias LDS as f32
        {
            float* myred = (float*)(wave ? (smem + 8192) : smem);  // 16 KB each
#pragma unroll
            for (int mt = 0; mt < 4; ++mt)
#pragma unroll
                for (int nt = 0; nt < 4; ++nt)
#pragma unroll
                    for (int r = 0; r < 4; ++r)
                        myred[(mt * 16 + lq * 4 + r) * 64 + nt * 16 + lr] = acc[mt][nt][r];
        }
        __syncthreads();
        {
            const float* rA = (const float*)smem;
            const float* rB = (const float*)(smem + 8192);
            const int n = iBase + lane;
            if (isL1) {
                const float bs = b1i[n] + b1h[n];
#pragma unroll 8
                for (int rr = 0; rr < 32; ++rr) {
                    const int row = wave * 32 + rr;
                    float v = rA[row * 64 + lane] + rB[row * 64 + lane] + bs;
                    H1wr[(size_t)(bBase + row) * Hn + n] = f2bf(fast_tanh(v));
                }
            } else {
                const float wv = w0ih[n];
                const float bs = b0i[n] + b0h[n];
#pragma unroll 8
                for (int rr = 0; rr < 32; ++rr) {
                    const int row = wave * 32 + rr;
                    const int bb = bBase + row;
                    const float xv = x[bb * Ln + s];
                    float v = rA[row * 64 + lane] + rB[row * 64 + lane] + xv * wv + bs;
                    H0wr[(size_t)bb * Hn + n] = f2bf(fast_tanh(v));
                }
            }
        }
    } else {
        // ================= FC(t = s-2), split-K across waves ==============
        if (s < 2) return;
        const int t = s - 2;
        const int bBase = ((l - 128) * 8 + xcd) * 64;     // [0,32)*64, XCD-spread
        const int k0 = wave * 512;
        const unsigned short* Ag = H1rd;
        const unsigned short* Bg = fcWb;
        unsigned short* const Al = smem + wave * 4096;           // 2 bufs x 2048
        unsigned short* const Bl = smem + 8192 + wave * 6144;    // 2 bufs x 3072
        float* red = (float*)(smem + 8192);    // 24 KB reduce area

        f32x4 acc[4][6];
#pragma unroll
        for (int i = 0; i < 4; ++i)
#pragma unroll
            for (int j = 0; j < 6; ++j) acc[i][j] = (f32x4){0.f, 0.f, 0.f, 0.f};

#pragma unroll
        for (int c = 0; c < 4; ++c)
            async16(Ag + (size_t)(bBase + c * 16 + srow) * Hn + k0 + scol, Al + c * 512);
#pragma unroll
        for (int c = 0; c < 6; ++c)
            async16(Bg + (size_t)(c * 16 + srow) * Hn + k0 + scol, Bl + c * 512);
        int buf = 0;
        for (int it = 0; it < 16; ++it) {
            if (it + 1 < 16) {
                LGKM_WAIT0;
                const int kt = k0 + (it + 1) * 32;
#pragma unroll
                for (int c = 0; c < 4; ++c)
                    async16(Ag + (size_t)(bBase + c * 16 + srow) * Hn + kt + scol,
                            Al + (buf ^ 1) * 2048 + c * 512);
#pragma unroll
                for (int c = 0; c < 6; ++c)
                    async16(Bg + (size_t)(c * 16 + srow) * Hn + kt + scol,
                            Bl + (buf ^ 1) * 3072 + c * 512);
                VM_WAIT(10);
            } else {
                VM_WAIT(0);
            }
            bf16x8 a[4], b[6];
#pragma unroll
            for (int i = 0; i < 4; ++i)
                a[i] = *(const bf16x8*)(Al + buf * 2048 + i * 512 + roff);
#pragma unroll
            for (int i = 0; i < 6; ++i)
                b[i] = *(const bf16x8*)(Bl + buf * 3072 + i * 512 + roff);
            __builtin_amdgcn_s_setprio(1);
#pragma unroll
            for (int mt = 0; mt < 4; ++mt)
#pragma unroll
                for (int nt = 0; nt < 6; ++nt)
                    acc[mt][nt] = __builtin_amdgcn_mfma_f32_16x16x32_bf16(
                        a[mt], b[nt], acc[mt][nt], 0, 0, 0);
            __builtin_amdgcn_s_setprio(0);
            buf ^= 1;
        }
        __syncthreads();
        if (wave == 1) {
#pragma unroll
            for (int mt = 0; mt < 4; ++mt)
#pragma unroll
                for (int nt = 0; nt < 6; ++nt)
#pragma unroll
                    for (int r = 0; r < 4; ++r)
                        red[(mt * 16 + lq * 4 + r) * 96 + nt * 16 + lr] = acc[mt][nt][r];
        }
        __syncthreads();
        if (wave == 0) {
#pragma unroll
            for (int mt = 0; mt < 4; ++mt)
#pragma unroll
                for (int r = 0; r < 4; ++r) {
                    const int row = mt * 16 + lq * 4 + r;
                    const size_t o = (size_t)(bBase + row) * (Ln * Vn) + (size_t)t * Vn;
#pragma unroll
                    for (int nt = 0; nt < 6; ++nt) {
                        const int v = nt * 16 + lr;
                        out[o + v] = acc[mt][nt][r] + red[row * 96 + v] + fcb[v];
                    }
                }
        }
    }
}

// ---------------------------------------------------------------------------
__global__ void f32_to_bf16(const float* __restrict__ in,
                            unsigned short* __restrict__ out, int n)
{
    int i = blockIdx.x * blockDim.x + threadIdx.x;
    int stride = gridDim.x * blockDim.x;
    for (; i < n; i += stride) out[i] = f2bf(in[i]);
}

__global__ void hidden_out(const unsigned short* __restrict__ h0,
                           const unsigned short* __restrict__ h1,
                           float* __restrict__ out)
{
    int i = blockIdx.x * 256 + threadIdx.x;
    out[i] = bf2f(h0[i]);
    out[(size_t)Bn * Hn + i] = bf2f(h1[i]);
}

// ---------------------------------------------------------------------------
// Sequential probability adjustment: one block per batch row b.
// Phase 1 (parallel over t): thread t computes max/argmax over cols != 1
// (m_ex, i_ex) plus v0, v1 — float4 loads, first-index tie rule.
// Phase 2 (thread 0): 96-step scalar recurrence on the precomputed stats;
// only col 1 is ever modified mid-scan, so the adjusted argmax follows from
// (v1 [+0.5], m_ex, i_ex) alone. Writes only the modified cells.
// ---------------------------------------------------------------------------
__global__ __launch_bounds__(128) void adjust_kernel(float* __restrict__ out)
{
    __shared__ float s_mex[Ln], s_v0[Ln], s_v1[Ln];
    __shared__ int   s_iex[Ln];
    const int b = blockIdx.x;
    const int t = threadIdx.x;
    float* row = out + (size_t)b * (Ln * Vn);

    if (t < Ln) {
        const float4* r4 = (const float4*)(row + t * Vn);
        float4 q = r4[0];
        float m = q.x; int im = 0;                 // col 0 included, col 1 excluded
        if (q.z > m) { m = q.z; im = 2; }
        if (q.w > m) { m = q.w; im = 3; }
        const float v0 = q.x, v1 = q.y;
        for (int jj = 1; jj < 24; ++jj) {
            float4 p = r4[jj];
            const int base = jj * 4;
            if (p.x > m) { m = p.x; im = base; }
            if (p.y > m) { m = p.y; im = base + 1; }
            if (p.z > m) { m = p.z; im = base + 2; }
            if (p.w > m) { m = p.w; im = base + 3; }
        }
        s_mex[t] = m; s_iex[t] = im; s_v0[t] = v0; s_v1[t] = v1;
    }
    __syncthreads();

    if (t == 0) {
        // argmax(row) with first-index ties: 1 wins over im iff v1>m, or
        // v1==m and im!=0 (im is in {0,2,3,...}).
        float v1p = s_v1[0]; float mp = s_mex[0]; int ip = s_iex[0];
        int prev = (v1p > mp || (v1p == mp && ip != 0)) ? 1 : ip;
        for (int k = 1; k < Ln; ++k) {
            const float v1c = s_v1[k];
            const float mc = s_mex[k];
            const int ic = s_iex[k];
            const int cur = (v1c > mc || (v1c == mc && ic != 0)) ? 1 : ic;
            float v1a = v1c;
            if (prev == 0 && cur != 1) {
                v1a = v1c + 0.5f;
                row[k * Vn + 1] = v1a;
            }
            if (k == Ln - 1 && cur == 0)
                row[k * Vn + 0] = s_v0[k] - 0.5f;
            prev = (v1a > mc || (v1a == mc && ic != 0)) ? 1 : ic;
        }
    }
}

// ---------------------------------------------------------------------------
extern "C" void kernel_launch(void* const* d_in, const int* in_sizes, int n_in,
                              void* d_out, int out_size, void* d_ws, size_t ws_size,
                              hipStream_t stream)
{
    const float* x    = (const float*)d_in[0];
    const float* w0ih = (const float*)d_in[1];
    const float* W0   = (const float*)d_in[2];
    const float* b0i  = (const float*)d_in[3];
    const float* b0h  = (const float*)d_in[4];
    const float* W1i  = (const float*)d_in[5];
    const float* W1h  = (const float*)d_in[6];
    const float* b1i  = (const float*)d_in[7];
    const float* b1h  = (const float*)d_in[8];
    const float* fcW  = (const float*)d_in[9];
    const float* fcb  = (const float*)d_in[10];
    float* out = (float*)d_out;

    const size_t HH = (size_t)Hn * Hn;
    const size_t BH = (size_t)Bn * Hn;
    unsigned short* ws = (unsigned short*)d_ws;
    unsigned short* W0b  = ws;
    unsigned short* W1ib = ws + HH;
    unsigned short* W1hb = ws + 2 * HH;
    unsigned short* fcWb = ws + 3 * HH;
    unsigned short* H0[2] = { ws + 4 * HH,          ws + 4 * HH + BH };
    unsigned short* H1[2] = { ws + 4 * HH + 2 * BH, ws + 4 * HH + 3 * BH };

    // h0(-1) lives in H0[0], h1(-1) in H1[0] (read at s=0 / s=1): zero them.
    hipMemsetAsync(H0[0], 0, BH * sizeof(unsigned short), stream);
    hipMemsetAsync(H1[0], 0, BH * sizeof(unsigned short), stream);

    f32_to_bf16<<<dim3(512), dim3(256), 0, stream>>>(W0,  W0b,  (int)HH);
    f32_to_bf16<<<dim3(512), dim3(256), 0, stream>>>(W1i, W1ib, (int)HH);
    f32_to_bf16<<<dim3(512), dim3(256), 0, stream>>>(W1h, W1hb, (int)HH);
    f32_to_bf16<<<dim3(64),  dim3(256), 0, stream>>>(fcW, fcWb, Vn * Hn);

    // Launch s computes: L0(s) [s<=95], L1(s-1) [s>=1], FC(s-2) [s>=2].
    // h0(t) lives in H0[(t+1)&1]; h1(t) in H1[(t+1)&1].
    for (int s = 0; s <= 97; ++s) {
        fused_step<<<dim3(1056), dim3(128), 0, stream>>>(
            s,
            H0[s & 1], H0[(s + 1) & 1],          // L0 read / write
            H1[(s + 1) & 1], H1[s & 1],          // h1(s-2) read / h1(s-1) write
            W0b, W1ib, W1hb, fcWb,
            w0ih, b0i, b0h, b1i, b1h, fcb, x, out);
    }

    adjust_kernel<<<dim3(Bn), dim3(128), 0, stream>>>(out);

    // final states: h0(95) = H0[0], h1(95) = H1[0]
    hidden_out<<<dim3((int)(BH / 256)), dim3(256), 0, stream>>>(
        H0[0], H1[0], out + (size_t)Bn * Ln * Vn);
}

// Round 5
// 2879.028 us; speedup vs baseline: 1.3197x; 1.3197x over previous
//
#include <hip/hip_runtime.h>

#define Bn 2048
#define Hn 1024
#define Ln 96
#define Vn 96

typedef short bf16x8 __attribute__((ext_vector_type(8)));
typedef float f32x4 __attribute__((ext_vector_type(4)));

// counted waits: immediates must be literals
#define VM_WAIT(n) asm volatile("s_waitcnt vmcnt(" #n ")" ::: "memory")
// raw barrier with compiler memory fence (no vmcnt drain, unlike __syncthreads)
#define BARRIER    asm volatile("s_barrier" ::: "memory")

__device__ __forceinline__ void async16(const void* g, void* l)
{
    __builtin_amdgcn_global_load_lds(
        (const __attribute__((address_space(1))) void*)g,
        (__attribute__((address_space(3))) void*)l, 16, 0, 0);
}

__device__ __forceinline__ unsigned short f2bf(float f)
{
    unsigned u = __float_as_uint(f);
    u += 0x7fff + ((u >> 16) & 1);          // round-to-nearest-even
    return (unsigned short)(u >> 16);
}

__device__ __forceinline__ float bf2f(unsigned short s)
{
    return __uint_as_float(((unsigned)s) << 16);
}

__device__ __forceinline__ float fast_tanh(float x)
{
    float e = __expf(2.0f * x);
    return 1.0f - __fdividef(2.0f, e + 1.0f);
}

// ---------------------------------------------------------------------------
// Fused step kernel, launch index s (0..97). Grid = 256 blocks x 512 thr
// (8 waves). 128x128 tiles halve staged traffic vs 64x64 (each byte staged
// is reused by 128 output rows/cols instead of 64): 394 -> 199 MB/step.
//   bid [0,128)   : L1(t=s-1) tile 128x128, K=2048 virtual concat:
//                   chunks 0-15 from (h0(s-1), W1i), 16-31 from (h1(s-2), W1h)
//                   -> acc carries the dual-GEMM sum, NO cross-wave reduce.
//   bid [128,256) : L0(t=s)   tile 128x128, K=1024 (16 chunks);
//                   blocks idx<16 then also run FC(t=s-2) tile 128x96
//                   (so L0+FC ~ 32 chunk-times ~ L1's 32 -> balanced).
// Cooperative staging (stage once, 8 waves read): K-chunk = 64 cols,
// double-buffered. Per chunk each wave issues 4 async16 (waves 0-3: A,
// waves 4-7: B), computes 16 MFMAs + 12 ds_read_b128 on the other buffer,
// then VM_WAIT(0) (own 4 loads, issued ~400cy earlier) + BARRIER.
// Per-wave output quadrant 64x32 -> acc[4][2], full-K sums, direct epilogue.
// LDS slots XOR-swizzled on BOTH the global source column and the ds_read
// address (verified rounds 1/3/4) -> max 2-way bank aliasing.
// LDS: A 2 bufs x 16 KB + B 2 bufs x 16 KB = 64 KB.
// ---------------------------------------------------------------------------
__global__ __launch_bounds__(512, 2) void fused_step(
    int s,
    const unsigned short* __restrict__ H0rd, unsigned short* __restrict__ H0wr,
    const unsigned short* __restrict__ H1rd, unsigned short* __restrict__ H1wr,
    const unsigned short* __restrict__ W0b,
    const unsigned short* __restrict__ W1ib, const unsigned short* __restrict__ W1hb,
    const unsigned short* __restrict__ fcWb,
    const float* __restrict__ w0ih,
    const float* __restrict__ b0i, const float* __restrict__ b0h,
    const float* __restrict__ b1i, const float* __restrict__ b1h,
    const float* __restrict__ fcb, const float* __restrict__ x,
    float* __restrict__ out)
{
    __shared__ __align__(16) unsigned short smem[32768];   // 64 KB
    const int tid = threadIdx.x;
    const int lane = tid & 63;
    const int wave = tid >> 6;                  // 0..7
    const int srow = lane >> 2;                 // staging row within 16-row chunk
    // stage-side swizzle: lane stores slot (lane&3), fetches global slot
    // (lane&3) ^ g(srow), g(row) = (row>>1)&3  [bijective per row]
    const int scol = ((lane & 3) ^ ((lane >> 3) & 3)) * 8;  // bf16 elems
    const int lr = lane & 15;
    const int lq = lane >> 4;
    // read-side swizzle: global slot lq of row lr lives at stored slot lq^g(lr)
    const int roff = lr * 32 + ((lq ^ ((lr >> 1) & 3)) * 8);
    const int bid = blockIdx.x;

    // LDS element offsets: A: buf*8192 + ks*4096 + c*512  (c = 16-row chunk)
    //                      B: 16384 + same
    if (bid < 128) {
        // ================= L1(t = s-1): 128x128, K = 2048 concat ==========
        if (s < 1 || s > 96) return;
        const int bBase = (bid >> 3) * 128;
        const int iBase = (bid & 7) * 128;

        f32x4 acc[4][2];
#pragma unroll
        for (int i = 0; i < 4; ++i) {
            acc[i][0] = (f32x4){0.f, 0.f, 0.f, 0.f};
            acc[i][1] = (f32x4){0.f, 0.f, 0.f, 0.f};
        }
        const int mC = (wave >> 2) * 4;         // A 16-row-chunk base for frags
        const int nC = (wave & 3) * 2;          // B chunk base

        auto stage = [&](int ks, int buf) {
            const unsigned short* Ag = (ks < 16) ? H0rd : H1rd;
            const unsigned short* Bg = (ks < 16) ? W1ib : W1hb;
            const int koff = (ks & 15) * 64;
            if (wave < 4) {
#pragma unroll
                for (int j = 0; j < 4; ++j) {
                    const int id = wave * 4 + j;
                    const int c = id & 7, k2 = id >> 3;
                    async16(Ag + (size_t)(bBase + c * 16 + srow) * Hn + koff + k2 * 32 + scol,
                            smem + buf * 8192 + k2 * 4096 + c * 512);
                }
            } else {
#pragma unroll
                for (int j = 0; j < 4; ++j) {
                    const int id = (wave - 4) * 4 + j;
                    const int c = id & 7, k2 = id >> 3;
                    async16(Bg + (size_t)(iBase + c * 16 + srow) * Hn + koff + k2 * 32 + scol,
                            smem + 16384 + buf * 8192 + k2 * 4096 + c * 512);
                }
            }
        };

        stage(0, 0); VM_WAIT(0); BARRIER;
        for (int kc = 0; kc < 32; ++kc) {
            if (kc + 1 < 32) stage(kc + 1, (kc + 1) & 1);
            const int buf = kc & 1;
#pragma unroll
            for (int k2 = 0; k2 < 2; ++k2) {
                bf16x8 a[4], b[2];
#pragma unroll
                for (int mt = 0; mt < 4; ++mt)
                    a[mt] = *(const bf16x8*)(smem + buf * 8192 + k2 * 4096 + (mC + mt) * 512 + roff);
#pragma unroll
                for (int nt = 0; nt < 2; ++nt)
                    b[nt] = *(const bf16x8*)(smem + 16384 + buf * 8192 + k2 * 4096 + (nC + nt) * 512 + roff);
                __builtin_amdgcn_s_setprio(1);
#pragma unroll
                for (int mt = 0; mt < 4; ++mt)
#pragma unroll
                    for (int nt = 0; nt < 2; ++nt)
                        acc[mt][nt] = __builtin_amdgcn_mfma_f32_16x16x32_bf16(
                            a[mt], b[nt], acc[mt][nt], 0, 0, 0);
                __builtin_amdgcn_s_setprio(0);
            }
            VM_WAIT(0); BARRIER;
        }
        // epilogue: wave owns rows [ (wave>>2)*64, +64 ), cols [ (wave&3)*32, +32 )
        {
            const int mB = (wave >> 2) * 64;
            const int nB = (wave & 3) * 32;
#pragma unroll
            for (int nt = 0; nt < 2; ++nt) {
                const int n = iBase + nB + nt * 16 + lr;
                const float bs = b1i[n] + b1h[n];
#pragma unroll
                for (int mt = 0; mt < 4; ++mt)
#pragma unroll
                    for (int r = 0; r < 4; ++r) {
                        const int row = mB + mt * 16 + lq * 4 + r;
                        float v = acc[mt][nt][r] + bs;
                        H1wr[(size_t)(bBase + row) * Hn + n] = f2bf(fast_tanh(v));
                    }
            }
        }
    } else {
        // ============ L0(t = s): 128x128, K = 1024; idx<16 then FC ========
        const int idx = bid - 128;
        if (s <= 95) {
            const int bBase = (idx >> 3) * 128;
            const int iBase = (idx & 7) * 128;

            f32x4 acc[4][2];
#pragma unroll
            for (int i = 0; i < 4; ++i) {
                acc[i][0] = (f32x4){0.f, 0.f, 0.f, 0.f};
                acc[i][1] = (f32x4){0.f, 0.f, 0.f, 0.f};
            }
            const int mC = (wave >> 2) * 4;
            const int nC = (wave & 3) * 2;

            auto stage = [&](int ks, int buf) {
                const int koff = ks * 64;
                if (wave < 4) {
#pragma unroll
                    for (int j = 0; j < 4; ++j) {
                        const int id = wave * 4 + j;
                        const int c = id & 7, k2 = id >> 3;
                        async16(H0rd + (size_t)(bBase + c * 16 + srow) * Hn + koff + k2 * 32 + scol,
                                smem + buf * 8192 + k2 * 4096 + c * 512);
                    }
                } else {
#pragma unroll
                    for (int j = 0; j < 4; ++j) {
                        const int id = (wave - 4) * 4 + j;
                        const int c = id & 7, k2 = id >> 3;
                        async16(W0b + (size_t)(iBase + c * 16 + srow) * Hn + koff + k2 * 32 + scol,
                                smem + 16384 + buf * 8192 + k2 * 4096 + c * 512);
                    }
                }
            };

            stage(0, 0); VM_WAIT(0); BARRIER;
            for (int kc = 0; kc < 16; ++kc) {
                if (kc + 1 < 16) stage(kc + 1, (kc + 1) & 1);
                const int buf = kc & 1;
#pragma unroll
                for (int k2 = 0; k2 < 2; ++k2) {
                    bf16x8 a[4], b[2];
#pragma unroll
                    for (int mt = 0; mt < 4; ++mt)
                        a[mt] = *(const bf16x8*)(smem + buf * 8192 + k2 * 4096 + (mC + mt) * 512 + roff);
#pragma unroll
                    for (int nt = 0; nt < 2; ++nt)
                        b[nt] = *(const bf16x8*)(smem + 16384 + buf * 8192 + k2 * 4096 + (nC + nt) * 512 + roff);
                    __builtin_amdgcn_s_setprio(1);
#pragma unroll
                    for (int mt = 0; mt < 4; ++mt)
#pragma unroll
                        for (int nt = 0; nt < 2; ++nt)
                            acc[mt][nt] = __builtin_amdgcn_mfma_f32_16x16x32_bf16(
                                a[mt], b[nt], acc[mt][nt], 0, 0, 0);
                    __builtin_amdgcn_s_setprio(0);
                }
                VM_WAIT(0); BARRIER;
            }
            {
                const int mB = (wave >> 2) * 64;
                const int nB = (wave & 3) * 32;
#pragma unroll
                for (int nt = 0; nt < 2; ++nt) {
                    const int n = iBase + nB + nt * 16 + lr;
                    const float wv = w0ih[n];
                    const float bs = b0i[n] + b0h[n];
#pragma unroll
                    for (int mt = 0; mt < 4; ++mt)
#pragma unroll
                        for (int r = 0; r < 4; ++r) {
                            const int row = mB + mt * 16 + lq * 4 + r;
                            const int bb = bBase + row;
                            const float xv = x[bb * Ln + s];
                            float v = acc[mt][nt][r] + xv * wv + bs;
                            H0wr[(size_t)bb * Hn + n] = f2bf(fast_tanh(v));
                        }
                }
            }
        }
        // ================= FC(t = s-2): 128x96, K = 1024 ==================
        if (idx < 16 && s >= 2) {
            __syncthreads();                    // reuse LDS after L0 (if it ran)
            const int t = s - 2;
            const int bBase2 = idx * 128;

            f32x4 acc2[2][3];
#pragma unroll
            for (int i = 0; i < 2; ++i)
#pragma unroll
                for (int j = 0; j < 3; ++j) acc2[i][j] = (f32x4){0.f, 0.f, 0.f, 0.f};
            const int mC2 = (wave >> 1) * 2;    // A chunk base (2 per wave-row)
            const int nC2 = (wave & 1) * 3;     // B chunk base

            auto stageF = [&](int ks, int buf) {
                const int koff = ks * 64;
                if (wave < 4) {
#pragma unroll
                    for (int j = 0; j < 4; ++j) {
                        const int id = wave * 4 + j;
                        const int c = id & 7, k2 = id >> 3;
                        async16(H1rd + (size_t)(bBase2 + c * 16 + srow) * Hn + koff + k2 * 32 + scol,
                                smem + buf * 8192 + k2 * 4096 + c * 512);
                    }
                } else if (wave < 7) {
#pragma unroll
                    for (int j = 0; j < 4; ++j) {
                        const int id = (wave - 4) * 4 + j;      // 0..11
                        const int k2 = id / 6, c = id % 6;
                        async16(fcWb + (size_t)(c * 16 + srow) * Hn + koff + k2 * 32 + scol,
                                smem + 16384 + buf * 8192 + k2 * 4096 + c * 512);
                    }
                }
            };

            stageF(0, 0); VM_WAIT(0); BARRIER;
            for (int kc = 0; kc < 16; ++kc) {
                if (kc + 1 < 16) stageF(kc + 1, (kc + 1) & 1);
                const int buf = kc & 1;
#pragma unroll
                for (int k2 = 0; k2 < 2; ++k2) {
                    bf16x8 a[2], b[3];
#pragma unroll
                    for (int mt = 0; mt < 2; ++mt)
                        a[mt] = *(const bf16x8*)(smem + buf * 8192 + k2 * 4096 + (mC2 + mt) * 512 + roff);
#pragma unroll
                    for (int nt = 0; nt < 3; ++nt)
                        b[nt] = *(const bf16x8*)(smem + 16384 + buf * 8192 + k2 * 4096 + (nC2 + nt) * 512 + roff);
                    __builtin_amdgcn_s_setprio(1);
#pragma unroll
                    for (int mt = 0; mt < 2; ++mt)
#pragma unroll
                        for (int nt = 0; nt < 3; ++nt)
                            acc2[mt][nt] = __builtin_amdgcn_mfma_f32_16x16x32_bf16(
                                a[mt], b[nt], acc2[mt][nt], 0, 0, 0);
                    __builtin_amdgcn_s_setprio(0);
                }
                VM_WAIT(0); BARRIER;
            }
            {
                const int mB2 = (wave >> 1) * 32;
                const int nB2 = (wave & 1) * 48;
#pragma unroll
                for (int mt = 0; mt < 2; ++mt)
#pragma unroll
                    for (int r = 0; r < 4; ++r) {
                        const int row = mB2 + mt * 16 + lq * 4 + r;
                        const size_t o = (size_t)(bBase2 + row) * (Ln * Vn) + (size_t)t * Vn;
#pragma unroll
                        for (int nt = 0; nt < 3; ++nt) {
                            const int n = nB2 + nt * 16 + lr;
                            out[o + n] = acc2[mt][nt][r] + fcb[n];
                        }
                    }
            }
        }
    }
}

// ---------------------------------------------------------------------------
__global__ void f32_to_bf16(const float* __restrict__ in,
                            unsigned short* __restrict__ out, int n)
{
    int i = blockIdx.x * blockDim.x + threadIdx.x;
    int stride = gridDim.x * blockDim.x;
    for (; i < n; i += stride) out[i] = f2bf(in[i]);
}

__global__ void hidden_out(const unsigned short* __restrict__ h0,
                           const unsigned short* __restrict__ h1,
                           float* __restrict__ out)
{
    int i = blockIdx.x * 256 + threadIdx.x;
    out[i] = bf2f(h0[i]);
    out[(size_t)Bn * Hn + i] = bf2f(h1[i]);
}

// ---------------------------------------------------------------------------
// Sequential probability adjustment: one block per batch row b.
// Phase 1 (parallel over t): thread t computes max/argmax over cols != 1
// (m_ex, i_ex) plus v0, v1 — float4 loads, first-index tie rule.
// Phase 2 (thread 0): 96-step scalar recurrence on the precomputed stats;
// only col 1 is ever modified mid-scan, so the adjusted argmax follows from
// (v1 [+0.5], m_ex, i_ex) alone. Writes only the modified cells.
// ---------------------------------------------------------------------------
__global__ __launch_bounds__(128) void adjust_kernel(float* __restrict__ out)
{
    __shared__ float s_mex[Ln], s_v0[Ln], s_v1[Ln];
    __shared__ int   s_iex[Ln];
    const int b = blockIdx.x;
    const int t = threadIdx.x;
    float* row = out + (size_t)b * (Ln * Vn);

    if (t < Ln) {
        const float4* r4 = (const float4*)(row + t * Vn);
        float4 q = r4[0];
        float m = q.x; int im = 0;                 // col 0 included, col 1 excluded
        if (q.z > m) { m = q.z; im = 2; }
        if (q.w > m) { m = q.w; im = 3; }
        const float v0 = q.x, v1 = q.y;
        for (int jj = 1; jj < 24; ++jj) {
            float4 p = r4[jj];
            const int base = jj * 4;
            if (p.x > m) { m = p.x; im = base; }
            if (p.y > m) { m = p.y; im = base + 1; }
            if (p.z > m) { m = p.z; im = base + 2; }
            if (p.w > m) { m = p.w; im = base + 3; }
        }
        s_mex[t] = m; s_iex[t] = im; s_v0[t] = v0; s_v1[t] = v1;
    }
    __syncthreads();

    if (t == 0) {
        // argmax(row) with first-index ties: 1 wins over im iff v1>m, or
        // v1==m and im!=0 (im is in {0,2,3,...}).
        float v1p = s_v1[0]; float mp = s_mex[0]; int ip = s_iex[0];
        int prev = (v1p > mp || (v1p == mp && ip != 0)) ? 1 : ip;
        for (int k = 1; k < Ln; ++k) {
            const float v1c = s_v1[k];
            const float mc = s_mex[k];
            const int ic = s_iex[k];
            const int cur = (v1c > mc || (v1c == mc && ic != 0)) ? 1 : ic;
            float v1a = v1c;
            if (prev == 0 && cur != 1) {
                v1a = v1c + 0.5f;
                row[k * Vn + 1] = v1a;
            }
            if (k == Ln - 1 && cur == 0)
                row[k * Vn + 0] = s_v0[k] - 0.5f;
            prev = (v1a > mc || (v1a == mc && ic != 0)) ? 1 : ic;
        }
    }
}

// ---------------------------------------------------------------------------
extern "C" void kernel_launch(void* const* d_in, const int* in_sizes, int n_in,
                              void* d_out, int out_size, void* d_ws, size_t ws_size,
                              hipStream_t stream)
{
    const float* x    = (const float*)d_in[0];
    const float* w0ih = (const float*)d_in[1];
    const float* W0   = (const float*)d_in[2];
    const float* b0i  = (const float*)d_in[3];
    const float* b0h  = (const float*)d_in[4];
    const float* W1i  = (const float*)d_in[5];
    const float* W1h  = (const float*)d_in[6];
    const float* b1i  = (const float*)d_in[7];
    const float* b1h  = (const float*)d_in[8];
    const float* fcW  = (const float*)d_in[9];
    const float* fcb  = (const float*)d_in[10];
    float* out = (float*)d_out;

    const size_t HH = (size_t)Hn * Hn;
    const size_t BH = (size_t)Bn * Hn;
    unsigned short* ws = (unsigned short*)d_ws;
    unsigned short* W0b  = ws;
    unsigned short* W1ib = ws + HH;
    unsigned short* W1hb = ws + 2 * HH;
    unsigned short* fcWb = ws + 3 * HH;
    unsigned short* H0[2] = { ws + 4 * HH,          ws + 4 * HH + BH };
    unsigned short* H1[2] = { ws + 4 * HH + 2 * BH, ws + 4 * HH + 3 * BH };

    // h0(-1) lives in H0[0], h1(-1) in H1[0] (read at s=0 / s=1): zero them.
    hipMemsetAsync(H0[0], 0, BH * sizeof(unsigned short), stream);
    hipMemsetAsync(H1[0], 0, BH * sizeof(unsigned short), stream);

    f32_to_bf16<<<dim3(512), dim3(256), 0, stream>>>(W0,  W0b,  (int)HH);
    f32_to_bf16<<<dim3(512), dim3(256), 0, stream>>>(W1i, W1ib, (int)HH);
    f32_to_bf16<<<dim3(512), dim3(256), 0, stream>>>(W1h, W1hb, (int)HH);
    f32_to_bf16<<<dim3(64),  dim3(256), 0, stream>>>(fcW, fcWb, Vn * Hn);

    // Launch s computes: L0(s) [s<=95], L1(s-1) [s>=1], FC(s-2) [s>=2].
    // h0(t) lives in H0[(t+1)&1]; h1(t) in H1[(t+1)&1].
    for (int s = 0; s <= 97; ++s) {
        fused_step<<<dim3(256), dim3(512), 0, stream>>>(
            s,
            H0[s & 1], H0[(s + 1) & 1],          // L0 read / write
            H1[(s + 1) & 1], H1[s & 1],          // h1(s-2) read / h1(s-1) write
            W0b, W1ib, W1hb, fcWb,
            w0ih, b0i, b0h, b1i, b1h, fcb, x, out);
    }

    adjust_kernel<<<dim3(Bn), dim3(128), 0, stream>>>(out);

    // final states: h0(95) = H0[0], h1(95) = H1[0]
    hidden_out<<<dim3((int)(BH / 256)), dim3(256), 0, stream>>>(
        H0[0], H1[0], out + (size_t)Bn * Ln * Vn);
}